// Round 9
// baseline (481.176 us; speedup 1.0000x reference)
//
#include <hip/hip_runtime.h>
#include <math.h>

#define NNODES 38400
#define KNBR 8
#define BK 32

typedef __attribute__((ext_vector_type(8))) short bf16x8;
typedef __attribute__((ext_vector_type(4))) short short4v;
typedef __attribute__((ext_vector_type(4))) float f32x4;

// Round-to-nearest-even split of fp32 into hi+lo bf16 (bit patterns).
static __device__ inline void split_bf16(float x, short& hi, short& lo) {
    unsigned u = __float_as_uint(x);
    unsigned r = (u + 0x7FFFu + ((u >> 16) & 1u)) & 0xFFFF0000u;
    hi = (short)(r >> 16);
    float rem = x - __uint_as_float(r);
    unsigned u2 = __float_as_uint(rem);
    unsigned r2 = (u2 + 0x7FFFu + ((u2 >> 16) & 1u));
    lo = (short)(r2 >> 16);
}

// Swizzled LDS element offset: row r (0..127) of 32 bf16, 16B chunk c (0..3),
// rotated by (r>>1)&3 -> ds_read_b128 across 16 rows is <=2-way (free).
static __device__ inline int lds_off(int r, int c) {
    return r * 32 + (((c + (r >> 1)) & 3) << 3);
}

// Async global->LDS, 16B per lane. LDS dest is wave-uniform base + lane*16.
static __device__ inline void gload16(const short* g, short* l) {
    __builtin_amdgcn_global_load_lds(
        (const __attribute__((address_space(1))) unsigned*)g,
        (__attribute__((address_space(3))) unsigned*)l, 16, 0, 0);
}

// ---- MFMA GEMM, global_load_lds staging, branch-free padded B ------------
__global__ __launch_bounds__(256) void gemm_lds(
    const short* __restrict__ Ahi, const short* __restrict__ Alo,
    int Kp, int nk,
    const short* __restrict__ Bhi, const short* __restrict__ Blo,
    int ldY, float* __restrict__ Y)
{
    const int row0 = blockIdx.x * 128;
    const int col0 = blockIdx.y * 128;
    const int tid = threadIdx.x;
    const int lane = tid & 63, wid = tid >> 6;
    const int wm = wid >> 1, wn = wid & 1;

    __shared__ short Ah_s[128 * 32];
    __shared__ short Al_s[128 * 32];
    __shared__ short Bh_s[128 * 32];
    __shared__ short Bl_s[128 * 32];

    const int li = lane >> 2;
    const int lc = lane & 3;
    const int r0 = wid * 32 + li;
    const int r1 = r0 + 16;
    const int c0 = (lc - (r0 >> 1)) & 3;   // logical chunk stored here
    const int c1 = (lc - (r1 >> 1)) & 3;

    const short* sAh0 = Ahi + (size_t)(row0 + r0) * Kp + c0 * 8;
    const short* sAh1 = Ahi + (size_t)(row0 + r1) * Kp + c1 * 8;
    const short* sAl0 = Alo + (size_t)(row0 + r0) * Kp + c0 * 8;
    const short* sAl1 = Alo + (size_t)(row0 + r1) * Kp + c1 * 8;
    const short* sBh0 = Bhi + (size_t)(col0 + r0) * Kp + c0 * 8;
    const short* sBh1 = Bhi + (size_t)(col0 + r1) * Kp + c1 * 8;
    const short* sBl0 = Blo + (size_t)(col0 + r0) * Kp + c0 * 8;
    const short* sBl1 = Blo + (size_t)(col0 + r1) * Kp + c1 * 8;

    short* dA0 = &Ah_s[(wid * 32) * 32];
    short* dA1 = &Ah_s[(wid * 32 + 16) * 32];
    short* dAl0 = &Al_s[(wid * 32) * 32];
    short* dAl1 = &Al_s[(wid * 32 + 16) * 32];
    short* dB0 = &Bh_s[(wid * 32) * 32];
    short* dB1 = &Bh_s[(wid * 32 + 16) * 32];
    short* dBl0 = &Bl_s[(wid * 32) * 32];
    short* dBl1 = &Bl_s[(wid * 32 + 16) * 32];

    f32x4 acc[4][4] = {};

    for (int ks = 0; ks < nk; ++ks) {
        const int ko = ks * BK;
        __syncthreads();
        gload16(sAh0 + ko, dA0);  gload16(sAh1 + ko, dA1);
        gload16(sAl0 + ko, dAl0); gload16(sAl1 + ko, dAl1);
        gload16(sBh0 + ko, dB0);  gload16(sBh1 + ko, dB1);
        gload16(sBl0 + ko, dBl0); gload16(sBl1 + ko, dBl1);
        __syncthreads();

        const int fr = lane & 15, g = lane >> 4;
        bf16x8 bh[4], bl[4];
#pragma unroll
        for (int f = 0; f < 4; ++f) {
            int bc = wn * 64 + f * 16 + fr;
            bh[f] = *(const bf16x8*)&Bh_s[lds_off(bc, g)];
            bl[f] = *(const bf16x8*)&Bl_s[lds_off(bc, g)];
        }
#pragma unroll
        for (int fm = 0; fm < 4; ++fm) {
            int ar = wm * 64 + fm * 16 + fr;
            bf16x8 ah = *(const bf16x8*)&Ah_s[lds_off(ar, g)];
            bf16x8 al = *(const bf16x8*)&Al_s[lds_off(ar, g)];
#pragma unroll
            for (int fn = 0; fn < 4; ++fn) {
                acc[fm][fn] = __builtin_amdgcn_mfma_f32_16x16x32_bf16(
                    bh[fn], ah, acc[fm][fn], 0, 0, 0);
                acc[fm][fn] = __builtin_amdgcn_mfma_f32_16x16x32_bf16(
                    bl[fn], ah, acc[fm][fn], 0, 0, 0);
                acc[fm][fn] = __builtin_amdgcn_mfma_f32_16x16x32_bf16(
                    bh[fn], al, acc[fm][fn], 0, 0, 0);
            }
        }
    }

#pragma unroll
    for (int fm = 0; fm < 4; ++fm) {
        int row = row0 + wm * 64 + fm * 16 + (lane & 15);
#pragma unroll
        for (int fn = 0; fn < 4; ++fn) {
            int col = col0 + wn * 64 + fn * 16 + (lane >> 4) * 4;
            *(f32x4*)(Y + (size_t)row * ldY + col) = acc[fm][fn];
        }
    }
}

// ---- split X (fp32 [N][50] -> hi/lo bf16 planes [N][64], zero-padded) ----
__global__ __launch_bounds__(256) void split_x(
    const float* __restrict__ X, short* __restrict__ Hhi, short* __restrict__ Hlo)
{
    const int total = NNODES * 16;
    for (int idx = blockIdx.x * 256 + threadIdx.x; idx < total;
         idx += gridDim.x * 256) {
        int n = idx >> 4, c = (idx & 15) << 2;
        short4v hi, lo;
#pragma unroll
        for (int j = 0; j < 4; ++j) {
            int e = c + j;
            float v = (e < 50) ? X[(size_t)n * 50 + e] : 0.f;
            short h, l; split_bf16(v, h, l);
            hi[j] = h; lo[j] = l;
        }
        *(short4v*)&Hhi[(size_t)n * 64 + c] = hi;
        *(short4v*)&Hlo[(size_t)n * 64 + c] = lo;
    }
}

// ---- build padded Wcat planes: rows [theta D | pad | phi D | pad] --------
__global__ __launch_bounds__(256) void split_wcat(
    const float* __restrict__ tw, const float* __restrict__ pw,
    int Ci, int Kp, int kpshift, int rows, int D, int phi,
    int chunkRows, int Dchunk,
    short* __restrict__ hi, short* __restrict__ lo)
{
    const int kp4 = Kp >> 2;
    const int total = rows * kp4;
    for (int idx = blockIdx.x * 256 + threadIdx.x; idx < total;
         idx += gridDim.x * 256) {
        const int r = idx >> (kpshift - 2);
        const int c = (idx & (kp4 - 1)) << 2;
        const int ch = r / chunkRows;
        const int w = r - ch * chunkRows;
        const float* src = nullptr;
        if (w < D) src = tw + (size_t)(ch * Dchunk + w) * Ci;
        else if (w >= phi && w < phi + D)
            src = pw + (size_t)(ch * Dchunk + (w - phi)) * Ci;
        short4v h4 = {}, l4 = {};
        if (src) {
#pragma unroll
            for (int j = 0; j < 4; ++j) {
                int e = c + j;
                float v = (e < Ci) ? src[e] : 0.f;
                short h, l; split_bf16(v, h, l);
                h4[j] = h; l4[j] = l;
            }
        }
        *(short4v*)&hi[(size_t)r * Kp + c] = h4;
        *(short4v*)&lo[(size_t)r * Kp + c] = l4;
    }
}

// ---- EdgeConv epilogue (layers 1-2): node-major flat, full-line writes ---
template <int LDY, int PHI, int CO, int KP, int KPSHIFT>
__global__ __launch_bounds__(256) void epi_flat(
    const float* __restrict__ Y, const int* __restrict__ nbr,
    const float* __restrict__ tb, const float* __restrict__ pb,
    short* __restrict__ Hhi, short* __restrict__ Hlo)
{
    const int total = NNODES << (KPSHIFT - 2);
    for (int idx = blockIdx.x * 256 + threadIdx.x; idx < total;
         idx += gridDim.x * 256) {
        const int n = idx >> (KPSHIFT - 2);
        const int c = (idx & ((KP >> 2) - 1)) << 2;
        if (c >= CO) {
            short4v z = {};
            *(short4v*)&Hhi[(size_t)n * KP + c] = z;
            *(short4v*)&Hlo[(size_t)n * KP + c] = z;
            continue;
        }
        const int* jn = nbr + n * KNBR;
        float4 m = make_float4(-INFINITY, -INFINITY, -INFINITY, -INFINITY);
#pragma unroll
        for (int k = 0; k < KNBR; ++k) {
            float4 v = *(const float4*)(Y + (size_t)jn[k] * LDY + c);
            m.x = fmaxf(m.x, v.x); m.y = fmaxf(m.y, v.y);
            m.z = fmaxf(m.z, v.z); m.w = fmaxf(m.w, v.w);
        }
        float4 yt = *(const float4*)(Y + (size_t)n * LDY + c);
        float4 yp = *(const float4*)(Y + (size_t)n * LDY + PHI + c);
        float4 b1 = *(const float4*)(tb + c);
        float4 b2 = *(const float4*)(pb + c);
        float o0 = tanhf(m.x - yt.x + b1.x + yp.x + b2.x);
        float o1 = tanhf(m.y - yt.y + b1.y + yp.y + b2.y);
        float o2 = tanhf(m.z - yt.z + b1.z + yp.z + b2.z);
        float o3 = tanhf(m.w - yt.w + b1.w + yp.w + b2.w);
        short4v hi, lo;
        short h, l;
        split_bf16(o0, h, l); hi[0] = h; lo[0] = l;
        split_bf16(o1, h, l); hi[1] = h; lo[1] = l;
        split_bf16(o2, h, l); hi[2] = h; lo[2] = l;
        split_bf16(o3, h, l); hi[3] = h; lo[3] = l;
        *(short4v*)&Hhi[(size_t)n * KP + c] = hi;
        *(short4v*)&Hlo[(size_t)n * KP + c] = lo;
    }
}

// ---- Layer-3 epilogue: 16 lanes/node, channel max -> gk[p*64+graph] ------
__global__ __launch_bounds__(256) void epi3_16(
    const float* __restrict__ Y,
    const int* __restrict__ nbr,
    const float* __restrict__ tb, const float* __restrict__ pb,
    float* __restrict__ gk, int first)
{
    const int node = blockIdx.x * 16 + (threadIdx.x >> 4);
    if (node >= NNODES) return;
    const int l16 = threadIdx.x & 15;
    const int* jn = nbr + node * KNBR;
    int j[KNBR];
#pragma unroll
    for (int k = 0; k < KNBR; ++k) j[k] = jn[k];
    float mx = -INFINITY;
#pragma unroll
    for (int it = 0; it < 2; ++it) {
        int c4 = l16 + it * 16;
        if (c4 >= 30) break;            // 120/4 chunks
        const int c = c4 << 2;
        float4 m = make_float4(-INFINITY, -INFINITY, -INFINITY, -INFINITY);
#pragma unroll
        for (int k = 0; k < KNBR; ++k) {
            float4 v = *(const float4*)(Y + (size_t)j[k] * 256 + c);
            m.x = fmaxf(m.x, v.x); m.y = fmaxf(m.y, v.y);
            m.z = fmaxf(m.z, v.z); m.w = fmaxf(m.w, v.w);
        }
        float4 yt = *(const float4*)(Y + (size_t)node * 256 + c);
        float4 yp = *(const float4*)(Y + (size_t)node * 256 + 128 + c);
        float4 b1 = *(const float4*)(tb + c);
        float4 b2 = *(const float4*)(pb + c);
        mx = fmaxf(mx, m.x - yt.x + b1.x + yp.x + b2.x);
        mx = fmaxf(mx, m.y - yt.y + b1.y + yp.y + b2.y);
        mx = fmaxf(mx, m.z - yt.z + b1.z + yp.z + b2.z);
        mx = fmaxf(mx, m.w - yt.w + b1.w + yp.w + b2.w);
    }
#pragma unroll
    for (int off = 1; off < 16; off <<= 1)
        mx = fmaxf(mx, __shfl_xor(mx, off));
    if (l16 == 0) {
        int g = node / 600;
        int p = node - g * 600;
        float* dst = &gk[p * 64 + g];
        *dst = first ? mx : fmaxf(*dst, mx);
    }
}

// ---- FC layer, split-K: one block per output unit, 4 c-slices x 64 graphs
// in: channel-major [CIN][64]. ACT 0: tanh -> out[o*64+g].
// ACT 1: clip -> out[g*COUT+o] (row-major final output).
template <int CIN, int COUT, int ACT>
__global__ __launch_bounds__(256) void fc_split(
    const float* __restrict__ in, const float* __restrict__ w,
    const float* __restrict__ b, float* __restrict__ out)
{
    const int o = blockIdx.x;
    const int t = threadIdx.x;
    const int g = t & 63, sl = t >> 6;
    constexpr int SL = (CIN + 3) / 4;
    const int cbeg = sl * SL;
    const int cend = (cbeg + SL < CIN) ? cbeg + SL : CIN;
    const float* wo = w + (size_t)o * CIN;
    float s = 0.f;
    for (int c = cbeg; c < cend; ++c)
        s = fmaf(in[c * 64 + g], wo[c], s);
    __shared__ float red[4][64];
    red[sl][g] = s;
    __syncthreads();
    if (sl == 0) {
        s = red[0][g] + red[1][g] + red[2][g] + red[3][g] + b[o];
        if (ACT == 0) out[o * 64 + g] = tanhf(s);
        else out[(size_t)g * COUT + o] = fminf(fmaxf(s, -2.f), 2.f);
    }
}

extern "C" void kernel_launch(void* const* d_in, const int* in_sizes, int n_in,
                              void* d_out, int out_size, void* d_ws, size_t ws_size,
                              hipStream_t stream)
{
    const float* inputs = (const float*)d_in[0];
    const int*   nbr    = (const int*)d_in[1];
    const float* t1w = (const float*)d_in[2];  const float* t1b = (const float*)d_in[3];
    const float* p1w = (const float*)d_in[4];  const float* p1b = (const float*)d_in[5];
    const float* t2w = (const float*)d_in[6];  const float* t2b = (const float*)d_in[7];
    const float* p2w = (const float*)d_in[8];  const float* p2b = (const float*)d_in[9];
    const float* t3w = (const float*)d_in[10]; const float* t3b = (const float*)d_in[11];
    const float* p3w = (const float*)d_in[12]; const float* p3b = (const float*)d_in[13];
    const float* fc1w = (const float*)d_in[14]; const float* fc1b = (const float*)d_in[15];
    const float* fc2w = (const float*)d_in[16]; const float* fc2b = (const float*)d_in[17];
    const float* fc3w = (const float*)d_in[18]; const float* fc3b = (const float*)d_in[19];
    const float* fc4w = (const float*)d_in[20]; const float* fc4b = (const float*)d_in[21];
    const float* fow  = (const float*)d_in[22]; const float* fob  = (const float*)d_in[23];
    float* out = (float*)d_out;

    const int N = NNODES;
    const int Kp1 = 64, Kp2 = 128, Kp3 = 256;
    const int nk1 = 2, nk2 = 4, nk3 = 7;   // K iterated: 64 / 128 / 224

    char* ws = (char*)d_ws;
    size_t off = 0;
    auto alloc = [&](size_t bytes) {
        void* p = ws + off;
        off = (off + bytes + 255) & ~(size_t)255;
        return p;
    };
    short* Xhi  = (short*)alloc((size_t)N * Kp1 * 2);
    short* Xlo  = (short*)alloc((size_t)N * Kp1 * 2);
    short* H1hi = (short*)alloc((size_t)N * Kp2 * 2);
    short* H1lo = (short*)alloc((size_t)N * Kp2 * 2);
    short* H2hi = (short*)alloc((size_t)N * Kp3 * 2);
    short* H2lo = (short*)alloc((size_t)N * Kp3 * 2);
    short* W1h = (short*)alloc((size_t)256 * Kp1 * 2);
    short* W1l = (short*)alloc((size_t)256 * Kp1 * 2);
    short* W2h = (short*)alloc((size_t)512 * Kp2 * 2);
    short* W2l = (short*)alloc((size_t)512 * Kp2 * 2);
    short* W3h = (short*)alloc((size_t)1280 * Kp3 * 2);
    short* W3l = (short*)alloc((size_t)1280 * Kp3 * 2);
    float* gk  = (float*)alloc((size_t)600 * 64 * 4);
    float* h1g = (float*)alloc((size_t)300 * 64 * 4);
    float* h2g = (float*)alloc((size_t)300 * 64 * 4);
    float* h3g = (float*)alloc((size_t)100 * 64 * 4);
    float* h4g = (float*)alloc((size_t)50 * 64 * 4);
    float* Y   = (float*)alloc((size_t)N * 512 * 4);   // max ldY=512

    // ---- prep: split X, build padded Wcat planes ----
    split_x<<<2400, 256, 0, stream>>>(inputs, Xhi, Xlo);
    split_wcat<<<64, 256, 0, stream>>>(t1w, p1w, 50, Kp1, 6, 256, 100, 128,
                                       256, 0, W1h, W1l);
    split_wcat<<<256, 256, 0, stream>>>(t2w, p2w, 100, Kp2, 7, 512, 200, 256,
                                        512, 0, W2h, W2l);
    split_wcat<<<320, 256, 0, stream>>>(t3w, p3w, 200, Kp3, 8, 1280, 120, 128,
                                        256, 120, W3h, W3l);

    // ---- EdgeConv 1: K 64, Y[*,256] theta@0 phi@128 ----
    gemm_lds<<<dim3(300, 2), 256, 0, stream>>>(Xhi, Xlo, Kp1, nk1,
                                               W1h, W1l, 256, Y);
    epi_flat<256, 128, 100, 128, 7><<<2400, 256, 0, stream>>>(
        Y, nbr, t1b, p1b, H1hi, H1lo);

    // ---- EdgeConv 2: K 128, Y[*,512] theta@0 phi@256 ----
    gemm_lds<<<dim3(300, 4), 256, 0, stream>>>(H1hi, H1lo, Kp2, nk2,
                                               W2h, W2l, 512, Y);
    epi_flat<512, 256, 200, 256, 8><<<4800, 256, 0, stream>>>(
        Y, nbr, t2b, p2b, H2hi, H2lo);

    // ---- EdgeConv 3: 5 chunks of D=120, Y[*,256] theta@0 phi@128 ----
    for (int ch = 0; ch < 5; ++ch) {
        const int d0 = ch * 120;
        gemm_lds<<<dim3(300, 2), 256, 0, stream>>>(
            H2hi, H2lo, Kp3, nk3,
            W3h + (size_t)ch * 256 * Kp3, W3l + (size_t)ch * 256 * Kp3,
            256, Y);
        epi3_16<<<2400, 256, 0, stream>>>(Y, nbr, t3b + d0, p3b + d0, gk,
                                          ch == 0 ? 1 : 0);
    }

    // ---- FC head: split-K chain ----
    fc_split<600, 300, 0><<<300, 256, 0, stream>>>(gk,  fc1w, fc1b, h1g);
    fc_split<300, 300, 0><<<300, 256, 0, stream>>>(h1g, fc2w, fc2b, h2g);
    fc_split<300, 100, 0><<<100, 256, 0, stream>>>(h2g, fc3w, fc3b, h3g);
    fc_split<100,  50, 0><<< 50, 256, 0, stream>>>(h3g, fc4w, fc4b, h4g);
    fc_split< 50,   9, 1><<<  9, 256, 0, stream>>>(h4g, fow,  fob,  out);
}